// Round 2
// baseline (43.981 us; speedup 1.0000x reference)
//
#include <hip/hip_runtime.h>
#include <math.h>

#define D 512
#define KP 1536            // packed K: [hi | lo | hi] x [hi | hi | lo]
#define NREL 512
#define NB 1024

typedef short bf16x8 __attribute__((ext_vector_type(8)));
typedef float f32x4 __attribute__((ext_vector_type(4)));

// ---- bf16 helpers (round-to-nearest-even), bit-ops to avoid API variance ---
__device__ __forceinline__ ushort f2bf(float f) {
    uint u = __float_as_uint(f);
    uint r = (u + 0x7fffu + ((u >> 16) & 1u)) >> 16;
    return (ushort)r;
}
__device__ __forceinline__ float bf2f(ushort h) {
    return __uint_as_float(((uint)h) << 16);
}

// ---- block-wide sum over 256 threads (4 waves of 64) -----------------------
__device__ __forceinline__ float block_reduce_256(float v, float* sbuf) {
#pragma unroll
    for (int off = 32; off > 0; off >>= 1)
        v += __shfl_down(v, off, 64);
    const int lane = threadIdx.x & 63;
    const int wid  = threadIdx.x >> 6;
    __syncthreads();
    if (lane == 0) sbuf[wid] = v;
    __syncthreads();
    return sbuf[0] + sbuf[1] + sbuf[2] + sbuf[3];
}

// ---- fused producer: rel_hyp rows (blocks 0..511) + query rows (512..1535) -
__global__ __launch_bounds__(256) void prep_kernel(
        const float* __restrict__ ent, const float* __restrict__ rel,
        const int* __restrict__ trip, const float* __restrict__ grot,
        ushort* __restrict__ A3, ushort* __restrict__ B3,
        float* __restrict__ x2, float* __restrict__ y2) {
    __shared__ float sbuf[4];
    const int t = threadIdx.x;          // dim pair (2t, 2t+1)
    const float c = 0.01f, sc = 0.1f;

    if (blockIdx.x < NREL) {
        // rel_hyp = exp_map_zero(rel_embedding); pack [hi | hi | lo]
        const int r = blockIdx.x;
        const float2 u = *(const float2*)(rel + (size_t)r * D + 2 * t);
        const float uu = block_reduce_256(u.x * u.x + u.y * u.y, sbuf);
        const float n  = fmaxf(sqrtf(uu), 1e-15f);
        const float es = tanhf(sc * n) / (sc * n);
        const float h1 = es * u.x, h2 = es * u.y;
        const float hh = block_reduce_256(h1 * h1 + h2 * h2, sbuf);
        const ushort hi1 = f2bf(h1), hi2 = f2bf(h2);
        const ushort lo1 = f2bf(h1 - bf2f(hi1)), lo2 = f2bf(h2 - bf2f(hi2));
        ushort* dst = B3 + (size_t)r * KP;
        *(ushort2*)(dst + 2 * t)         = make_ushort2(hi1, hi2);
        *(ushort2*)(dst + D + 2 * t)     = make_ushort2(hi1, hi2);
        *(ushort2*)(dst + 2 * D + 2 * t) = make_ushort2(lo1, lo2);
        if (t == 0) y2[r] = hh;
    } else {
        // query row; pack [hi | lo | hi]
        const int b = blockIdx.x - NREL;
        const int sidx = trip[b * 3 + 0];
        const int oidx = trip[b * 3 + 2];
        const float2 s = *(const float2*)(ent + (size_t)sidx * D + 2 * t);
        const float2 o = *(const float2*)(ent + (size_t)oidx * D + 2 * t);

        const float ss  = block_reduce_256(s.x * s.x + s.y * s.y, sbuf);
        const float n_s = fmaxf(sqrtf(ss), 1e-15f);
        const float arg = fminf(fmaxf(sc * n_s, -1.0f + 1e-7f), 1.0f - 1e-7f);
        const float ls  = atanhf(arg) / (sc * n_s);
        const float x1  = ls * s.x, x2e = ls * s.y;

        float sa, ca;
        sincosf(grot[t], &sa, &ca);
        const float u1 = ca * x1 - sa * x2e;
        const float u2 = sa * x1 + ca * x2e;

        const float uu  = block_reduce_256(u1 * u1 + u2 * u2, sbuf);
        const float n_u = fmaxf(sqrtf(uu), 1e-15f);
        const float es  = tanhf(sc * n_u) / (sc * n_u);
        const float r1  = es * u1, r2 = es * u2;

        const float rr = block_reduce_256(r1 * r1 + r2 * r2, sbuf);
        const float oo = block_reduce_256(o.x * o.x + o.y * o.y, sbuf);
        const float ro = block_reduce_256(r1 * o.x + r2 * o.y, sbuf);
        const float xy  = -ro;
        const float A1  = 1.0f + 2.0f * c * xy + c * oo;
        const float B1  = 1.0f - c * rr;
        const float den = fmaxf(1.0f + 2.0f * c * xy + c * c * rr * oo, 1e-15f);
        const float q1  = (A1 * (-r1) + B1 * o.x) / den;
        const float q2  = (A1 * (-r2) + B1 * o.y) / den;

        const float qq = block_reduce_256(q1 * q1 + q2 * q2, sbuf);
        const ushort hi1 = f2bf(q1), hi2 = f2bf(q2);
        const ushort lo1 = f2bf(q1 - bf2f(hi1)), lo2 = f2bf(q2 - bf2f(hi2));
        ushort* dst = A3 + (size_t)b * KP;
        *(ushort2*)(dst + 2 * t)         = make_ushort2(hi1, hi2);
        *(ushort2*)(dst + D + 2 * t)     = make_ushort2(lo1, lo2);
        *(ushort2*)(dst + 2 * D + 2 * t) = make_ushort2(hi1, hi2);
        if (t == 0) x2[b] = qq;
    }
}

// ---- MFMA score GEMM: 64x64 tile / block, 4 waves 2x2, frags 2x2 -----------
__global__ __launch_bounds__(256) void score_mfma(
        const ushort* __restrict__ A3, const ushort* __restrict__ B3,
        const float* __restrict__ x2, const float* __restrict__ y2,
        const float* __restrict__ bias, float* __restrict__ out) {
    const int t = threadIdx.x;
    const int wid = t >> 6, lane = t & 63;
    const int wm = wid >> 1, wn = wid & 1;
    const int m0 = blockIdx.y * 64 + wm * 32;
    const int n0 = blockIdx.x * 64 + wn * 32;
    const int row = lane & 15, kg = lane >> 4;   // frag: 8 contiguous K @ kg*8

    const bf16x8* pa0 = (const bf16x8*)(A3 + (size_t)(m0 + row) * KP) + kg;
    const bf16x8* pa1 = (const bf16x8*)(A3 + (size_t)(m0 + 16 + row) * KP) + kg;
    const bf16x8* pb0 = (const bf16x8*)(B3 + (size_t)(n0 + row) * KP) + kg;
    const bf16x8* pb1 = (const bf16x8*)(B3 + (size_t)(n0 + 16 + row) * KP) + kg;

    f32x4 acc[2][2] = {};
#pragma unroll 4
    for (int k8 = 0; k8 < KP / 8; k8 += 4) {     // k advances 32 per iter
        const bf16x8 a0 = pa0[k8], a1 = pa1[k8];
        const bf16x8 b0 = pb0[k8], b1 = pb1[k8];
        acc[0][0] = __builtin_amdgcn_mfma_f32_16x16x32_bf16(a0, b0, acc[0][0], 0, 0, 0);
        acc[0][1] = __builtin_amdgcn_mfma_f32_16x16x32_bf16(a0, b1, acc[0][1], 0, 0, 0);
        acc[1][0] = __builtin_amdgcn_mfma_f32_16x16x32_bf16(a1, b0, acc[1][0], 0, 0, 0);
        acc[1][1] = __builtin_amdgcn_mfma_f32_16x16x32_bf16(a1, b1, acc[1][1], 0, 0, 0);
    }

    // C/D layout: col = lane&15, row = (lane>>4)*4 + reg
    const float c = 0.01f;
    const int crow = (lane >> 4) * 4;
    const int ccol = lane & 15;
#pragma unroll
    for (int i = 0; i < 2; ++i) {
#pragma unroll
        for (int r = 0; r < 4; ++r) {
            const int m = m0 + i * 16 + crow + r;
            const float X2 = x2[m];
            const float B1 = 1.0f - c * X2;
#pragma unroll
            for (int j = 0; j < 2; ++j) {
                const int n  = n0 + j * 16 + ccol;
                const float qd = acc[i][j][r];
                const float Y2 = y2[n];
                const float A1  = 1.0f - 2.0f * c * qd + c * Y2;
                const float den = fmaxf(1.0f - 2.0f * c * qd + c * c * X2 * Y2, 1e-15f);
                const float num2 = A1 * A1 * X2 - 2.0f * A1 * B1 * qd + B1 * B1 * Y2;
                out[(size_t)m * NREL + n] = -(num2 / (den * den)) + bias[n];
            }
        }
    }
}

extern "C" void kernel_launch(void* const* d_in, const int* in_sizes, int n_in,
                              void* d_out, int out_size, void* d_ws, size_t ws_size,
                              hipStream_t stream) {
    const float* ent  = (const float*)d_in[0];   // (20000, 512)
    const float* rel  = (const float*)d_in[1];   // (512, 512)
    const int*   trip = (const int*)d_in[2];     // (1024, 3)
    const float* grot = (const float*)d_in[3];   // (256,)
    const float* bias = (const float*)d_in[4];   // (512,)
    float* out = (float*)d_out;                  // (1024, 512)

    ushort* A3 = (ushort*)d_ws;                  // 1024*1536 bf16
    ushort* B3 = A3 + (size_t)NB * KP;           // 512*1536 bf16
    float*  x2 = (float*)(B3 + (size_t)NREL * KP);
    float*  y2 = x2 + NB;

    prep_kernel<<<dim3(NREL + NB), dim3(256), 0, stream>>>(
        ent, rel, trip, grot, A3, B3, x2, y2);
    score_mfma<<<dim3(NREL / 64, NB / 64), dim3(256), 0, stream>>>(
        A3, B3, x2, y2, bias, out);
}

// Round 3
// 29.964 us; speedup vs baseline: 1.4678x; 1.4678x over previous
//
#include <hip/hip_runtime.h>
#include <math.h>

#define D 512
#define KP 1024            // packed K: A=[q_hi | q_lo], B=[r_hi | r_hi]
#define NREL 512
#define NB 1024

typedef short bf16x8 __attribute__((ext_vector_type(8)));
typedef float f32x4 __attribute__((ext_vector_type(4)));

// ---- bf16 helpers (round-to-nearest-even) ----------------------------------
__device__ __forceinline__ ushort f2bf(float f) {
    uint u = __float_as_uint(f);
    uint r = (u + 0x7fffu + ((u >> 16) & 1u)) >> 16;
    return (ushort)r;
}
__device__ __forceinline__ float bf2f(ushort h) {
    return __uint_as_float(((uint)h) << 16);
}

// ---- block-wide sum over 256 threads (4 waves of 64) -----------------------
__device__ __forceinline__ float block_reduce_256(float v, float* sbuf) {
#pragma unroll
    for (int off = 32; off > 0; off >>= 1)
        v += __shfl_down(v, off, 64);
    const int lane = threadIdx.x & 63;
    const int wid  = threadIdx.x >> 6;
    __syncthreads();
    if (lane == 0) sbuf[wid] = v;
    __syncthreads();
    return sbuf[0] + sbuf[1] + sbuf[2] + sbuf[3];
}

// ---- fused producer: rel_hyp rows (blocks 0..511) + query rows (512..1535) -
__global__ __launch_bounds__(256) void prep_kernel(
        const float* __restrict__ ent, const float* __restrict__ rel,
        const int* __restrict__ trip, const float* __restrict__ grot,
        ushort* __restrict__ A3, ushort* __restrict__ B3,
        float* __restrict__ x2, float* __restrict__ y2) {
    __shared__ float sbuf[4];
    const int t = threadIdx.x;          // dim pair (2t, 2t+1)
    const float c = 0.01f, sc = 0.1f;

    if (blockIdx.x < NREL) {
        // rel_hyp = exp_map_zero(rel_embedding); pack [hi | hi]
        const int r = blockIdx.x;
        const float2 u = *(const float2*)(rel + (size_t)r * D + 2 * t);
        const float uu = block_reduce_256(u.x * u.x + u.y * u.y, sbuf);
        const float n  = fmaxf(sqrtf(uu), 1e-15f);
        const float es = tanhf(sc * n) / (sc * n);
        const float h1 = es * u.x, h2 = es * u.y;
        const float hh = block_reduce_256(h1 * h1 + h2 * h2, sbuf);
        const ushort hi1 = f2bf(h1), hi2 = f2bf(h2);
        ushort* dst = B3 + (size_t)r * KP;
        *(ushort2*)(dst + 2 * t)     = make_ushort2(hi1, hi2);
        *(ushort2*)(dst + D + 2 * t) = make_ushort2(hi1, hi2);
        if (t == 0) y2[r] = hh;
    } else {
        // query row; pack [hi | lo]
        const int b = blockIdx.x - NREL;
        const int sidx = trip[b * 3 + 0];
        const int oidx = trip[b * 3 + 2];
        const float2 s = *(const float2*)(ent + (size_t)sidx * D + 2 * t);
        const float2 o = *(const float2*)(ent + (size_t)oidx * D + 2 * t);

        const float ss  = block_reduce_256(s.x * s.x + s.y * s.y, sbuf);
        const float n_s = fmaxf(sqrtf(ss), 1e-15f);
        const float arg = fminf(fmaxf(sc * n_s, -1.0f + 1e-7f), 1.0f - 1e-7f);
        const float ls  = atanhf(arg) / (sc * n_s);
        const float x1  = ls * s.x, x2e = ls * s.y;

        float sa, ca;
        sincosf(grot[t], &sa, &ca);
        const float u1 = ca * x1 - sa * x2e;
        const float u2 = sa * x1 + ca * x2e;

        const float uu  = block_reduce_256(u1 * u1 + u2 * u2, sbuf);
        const float n_u = fmaxf(sqrtf(uu), 1e-15f);
        const float es  = tanhf(sc * n_u) / (sc * n_u);
        const float r1  = es * u1, r2 = es * u2;

        const float rr = block_reduce_256(r1 * r1 + r2 * r2, sbuf);
        const float oo = block_reduce_256(o.x * o.x + o.y * o.y, sbuf);
        const float ro = block_reduce_256(r1 * o.x + r2 * o.y, sbuf);
        const float xy  = -ro;
        const float A1  = 1.0f + 2.0f * c * xy + c * oo;
        const float B1  = 1.0f - c * rr;
        const float den = fmaxf(1.0f + 2.0f * c * xy + c * c * rr * oo, 1e-15f);
        const float q1  = (A1 * (-r1) + B1 * o.x) / den;
        const float q2  = (A1 * (-r2) + B1 * o.y) / den;

        const float qq = block_reduce_256(q1 * q1 + q2 * q2, sbuf);
        const ushort hi1 = f2bf(q1), hi2 = f2bf(q2);
        const ushort lo1 = f2bf(q1 - bf2f(hi1)), lo2 = f2bf(q2 - bf2f(hi2));
        ushort* dst = A3 + (size_t)b * KP;
        *(ushort2*)(dst + 2 * t)     = make_ushort2(hi1, hi2);
        *(ushort2*)(dst + D + 2 * t) = make_ushort2(lo1, lo2);
        if (t == 0) x2[b] = qq;
    }
}

// ---- MFMA score GEMM: 64x32 tile / 128-thread block, 2 waves of 32x32 ------
__global__ __launch_bounds__(128) void score_mfma(
        const ushort* __restrict__ A3, const ushort* __restrict__ B3,
        const float* __restrict__ x2, const float* __restrict__ y2,
        const float* __restrict__ bias, float* __restrict__ out) {
    const int t = threadIdx.x;
    const int wid = t >> 6, lane = t & 63;
    const int m0 = blockIdx.y * 64 + wid * 32;
    const int n0 = blockIdx.x * 32;
    const int row = lane & 15, kg = lane >> 4;   // frag: 8 contiguous K @ kg*8

    const bf16x8* pa0 = (const bf16x8*)(A3 + (size_t)(m0 + row) * KP) + kg;
    const bf16x8* pa1 = (const bf16x8*)(A3 + (size_t)(m0 + 16 + row) * KP) + kg;
    const bf16x8* pb0 = (const bf16x8*)(B3 + (size_t)(n0 + row) * KP) + kg;
    const bf16x8* pb1 = (const bf16x8*)(B3 + (size_t)(n0 + 16 + row) * KP) + kg;

    f32x4 acc[2][2] = {};
#pragma unroll 4
    for (int k8 = 0; k8 < KP / 8; k8 += 4) {     // k advances 32 per iter
        const bf16x8 a0 = pa0[k8], a1 = pa1[k8];
        const bf16x8 b0 = pb0[k8], b1 = pb1[k8];
        acc[0][0] = __builtin_amdgcn_mfma_f32_16x16x32_bf16(a0, b0, acc[0][0], 0, 0, 0);
        acc[0][1] = __builtin_amdgcn_mfma_f32_16x16x32_bf16(a0, b1, acc[0][1], 0, 0, 0);
        acc[1][0] = __builtin_amdgcn_mfma_f32_16x16x32_bf16(a1, b0, acc[1][0], 0, 0, 0);
        acc[1][1] = __builtin_amdgcn_mfma_f32_16x16x32_bf16(a1, b1, acc[1][1], 0, 0, 0);
    }

    // C/D layout: col = lane&15, row = (lane>>4)*4 + reg
    const float c = 0.01f;
    const int crow = (lane >> 4) * 4;
    const int ccol = lane & 15;
#pragma unroll
    for (int i = 0; i < 2; ++i) {
#pragma unroll
        for (int r = 0; r < 4; ++r) {
            const int m = m0 + i * 16 + crow + r;
            const float X2 = x2[m];
            const float B1 = 1.0f - c * X2;
#pragma unroll
            for (int j = 0; j < 2; ++j) {
                const int n  = n0 + j * 16 + ccol;
                const float qd = acc[i][j][r];
                const float Y2 = y2[n];
                const float A1  = 1.0f - 2.0f * c * qd + c * Y2;
                const float den = fmaxf(1.0f - 2.0f * c * qd + c * c * X2 * Y2, 1e-15f);
                const float num2 = A1 * A1 * X2 - 2.0f * A1 * B1 * qd + B1 * B1 * Y2;
                out[(size_t)m * NREL + n] = -(num2 / (den * den)) + bias[n];
            }
        }
    }
}

extern "C" void kernel_launch(void* const* d_in, const int* in_sizes, int n_in,
                              void* d_out, int out_size, void* d_ws, size_t ws_size,
                              hipStream_t stream) {
    const float* ent  = (const float*)d_in[0];   // (20000, 512)
    const float* rel  = (const float*)d_in[1];   // (512, 512)
    const int*   trip = (const int*)d_in[2];     // (1024, 3)
    const float* grot = (const float*)d_in[3];   // (256,)
    const float* bias = (const float*)d_in[4];   // (512,)
    float* out = (float*)d_out;                  // (1024, 512)

    ushort* A3 = (ushort*)d_ws;                  // 1024*1024 bf16
    ushort* B3 = A3 + (size_t)NB * KP;           // 512*1024 bf16
    float*  x2 = (float*)(B3 + (size_t)NREL * KP);
    float*  y2 = x2 + NB;

    prep_kernel<<<dim3(NREL + NB), dim3(256), 0, stream>>>(
        ent, rel, trip, grot, A3, B3, x2, y2);
    score_mfma<<<dim3(NREL / 32, NB / 64), dim3(128), 0, stream>>>(
        A3, B3, x2, y2, bias, out);
}